// Round 1
// baseline (125.249 us; speedup 1.0000x reference)
//
#include <hip/hip_runtime.h>
#include <hip/hip_cooperative_groups.h>
#include <math.h>

namespace cg = cooperative_groups;

#define Bn 2048
#define Dn 512
#define Cn 16384

typedef float v4f __attribute__((ext_vector_type(4)));

#define WAIT_VM4()  asm volatile("s_waitcnt vmcnt(4)" ::: "memory")
#define WAIT_VM0()  asm volatile("s_waitcnt vmcnt(0)" ::: "memory")
#define RAW_BAR()   asm volatile("s_barrier" ::: "memory")
#define LGKM0_BAR() asm volatile("s_waitcnt lgkmcnt(0)\n\ts_barrier" ::: "memory")

__device__ __forceinline__ void async16(const void* g, void* l) {
  __builtin_amdgcn_global_load_lds(
      (const __attribute__((address_space(1))) char*)g,
      (__attribute__((address_space(3))) char*)l, 16, 0, 0);
}

// ================= shared device pieces (both paths) =================

__device__ __forceinline__ void prep_load(
    int row, int lane, const float* __restrict__ w, const float* __restrict__ x,
    float4& a, float4& b)
{
  const float* src = (row < Cn) ? (w + (size_t)row * Dn) : (x + (size_t)(row - Cn) * Dn);
  const float4* s4 = (const float4*)src;
  a = s4[lane * 2];
  b = s4[lane * 2 + 1];
}

// wave-per-row: norm, scales, fp8 e4m3 conversion (16x prescale); inputs preloaded
__device__ __forceinline__ void prep_row_vals(
    int row, int lane, float4 a, float4 b,
    char* __restrict__ wq8, char* __restrict__ xq8,
    float* __restrict__ fscale, float* __restrict__ ysqA, float* __restrict__ yrA,
    float* __restrict__ xsA, float* __restrict__ xrA)
{
  bool isW = row < Cn;
  float ss = a.x * a.x + a.y * a.y + a.z * a.z + a.w * a.w
           + b.x * b.x + b.y * b.y + b.z * b.z + b.w * b.w;
  #pragma unroll
  for (int d = 1; d < 64; d <<= 1) ss += __shfl_xor(ss, d);

  int w0 = __builtin_amdgcn_cvt_pk_fp8_f32(a.x * 16.f, a.y * 16.f, 0, false);
  w0     = __builtin_amdgcn_cvt_pk_fp8_f32(a.z * 16.f, a.w * 16.f, w0, true);
  int w1 = __builtin_amdgcn_cvt_pk_fp8_f32(b.x * 16.f, b.y * 16.f, 0, false);
  w1     = __builtin_amdgcn_cvt_pk_fp8_f32(b.z * 16.f, b.w * 16.f, w1, true);
  char* dst = isW ? (wq8 + (size_t)row * Dn) : (xq8 + (size_t)(row - Cn) * Dn);
  ((int2*)dst)[lane] = make_int2(w0, w1);

  if (lane == 0) {
    if (isW) {
      float n = fmaxf(sqrtf(ss), 1e-7f);
      // fast tanh: t = (e^{2n}-1)/(e^{2n}+1); clamp arg (tanh(10)==1 in fp32)
      float e2 = __expf(2.f * fminf(n, 10.f));
      float t = (e2 - 1.f) * __builtin_amdgcn_rcpf(e2 + 1.f);
      float tc = fminf(t, 0.95f);   // radius clip folded into scale
      fscale[row] = tc / n;
      float ys = tc * tc;
      ysqA[row] = ys;
      yrA[row] = 1.f / (1.f - fminf(ys, 1.f - 1e-5f));
    } else {
      int r = row - Cn;
      xsA[r] = ss;
      xrA[r] = 1.f / (1.f - fminf(ss, 1.f - 1e-5f));
    }
  }
}

// one 128x128 fp8 GEMM job: 2-buffer (32 KB) vmcnt pipeline (R8-proven ordering)
__device__ __forceinline__ void gemm_job(
    int job, int tid, char* lds,
    const char* __restrict__ xq8, const char* __restrict__ wq8,
    const float* __restrict__ fscale, const float* __restrict__ ysqA,
    const float* __restrict__ yrA, const float* __restrict__ xsA,
    const float* __restrict__ xrA, float* __restrict__ partials)
{
  const int xcd = job & 7;
  const int loc = job >> 3;
  const int mt  = loc & 15;
  const int nt  = (xcd << 4) | (loc >> 4);
  const int mBase = mt * 128;
  const int nBase = nt * 128;
  const int lane = tid & 63;
  const int wv = tid >> 6;
  const int quad = lane >> 4;
  const int l16 = lane & 15;
  const int waveM = wv >> 1;
  const int waveN = wv & 1;

  v4f acc[4][4];
  #pragma unroll
  for (int i = 0; i < 4; ++i)
    #pragma unroll
    for (int j = 0; j < 4; ++j)
      acc[i][j] = (v4f){0.f, 0.f, 0.f, 0.f};

  // staging: slot s -> r=s>>2, global chunk col (s&3)^((r>>1)&3)  (conflict-free)
  const int s0 = tid, s1 = tid + 256;
  const int r0 = s0 >> 2, c0 = (s0 & 3) ^ ((r0 >> 1) & 3);
  const int r1 = s1 >> 2, c1 = (s1 & 3) ^ ((r1 >> 1) & 3);
  const char* gA0 = xq8 + (size_t)(mBase + r0) * Dn + c0 * 16;
  const char* gA1 = xq8 + (size_t)(mBase + r1) * Dn + c1 * 16;
  const char* gW0 = wq8 + (size_t)(nBase + r0) * Dn + c0 * 16;
  const char* gW1 = wq8 + (size_t)(nBase + r1) * Dn + c1 * 16;
  const int lo0 = s0 * 16, lo1 = s1 * 16;

  const int kx = (l16 >> 1) & 3;
  int aoff[2], boff[2];
  #pragma unroll
  for (int s = 0; s < 2; ++s) {
    int chunk = (2 * s + (quad >> 1)) ^ kx;
    aoff[s] = (waveM * 64 + l16) * 64 + chunk * 16 + (quad & 1) * 8;
    boff[s] = (waveN * 64 + l16) * 64 + chunk * 16 + (quad & 1) * 8;
  }

  // prologue: tiles 0,1 -> buffers 0,1 (8 loads in flight)
  #pragma unroll
  for (int t = 0; t < 2; ++t) {
    char* Ab = lds + t * 16384;
    char* Wb = Ab + 8192;
    async16(gA0 + t * 64, Ab + lo0);
    async16(gA1 + t * 64, Ab + lo1);
    async16(gW0 + t * 64, Wb + lo0);
    async16(gW1 + t * 64, Wb + lo1);
  }

  #pragma unroll
  for (int kt = 0; kt < 8; ++kt) {
    const int cur = kt & 1;
    if (kt < 7) { WAIT_VM4(); } else { WAIT_VM0(); }  // tile kt landed (this wave)
    RAW_BAR();                                         // ...for all waves
    char* Ab = lds + cur * 16384;
    char* Wb = Ab + 8192;
    long af[4][2], bf[4][2];
    #pragma unroll
    for (int s = 0; s < 2; ++s) {
      #pragma unroll
      for (int i = 0; i < 4; ++i) af[i][s] = *(const long*)(Ab + aoff[s] + i * 1024);
      #pragma unroll
      for (int j = 0; j < 4; ++j) bf[j][s] = *(const long*)(Wb + boff[s] + j * 1024);
    }
    #pragma unroll
    for (int s = 0; s < 2; ++s)
      #pragma unroll
      for (int i = 0; i < 4; ++i)
        #pragma unroll
        for (int j = 0; j < 4; ++j)
          acc[i][j] = __builtin_amdgcn_mfma_f32_16x16x32_fp8_fp8(af[i][s], bf[j][s], acc[i][j], 0, 0, 0);
    LGKM0_BAR();  // all waves' reads of buf[cur] drained -> safe to rewrite
    if (kt + 2 < 8) {  // tile kt+2 into buf[cur]
      async16(gA0 + (kt + 2) * 64, Ab + lo0);
      async16(gA1 + (kt + 2) * 64, Ab + lo1);
      async16(gW0 + (kt + 2) * 64, Wb + lo0);
      async16(gW1 + (kt + 2) * 64, Wb + lo1);
    }
  }

  // epilogue: e^{+64}-scaled partial sums; 1/256 folds the 16x prescale
  float ysqj[4], yrj[4], gj[4];
  #pragma unroll
  for (int j = 0; j < 4; ++j) {
    int col = nBase + waveN * 64 + j * 16 + l16;
    gj[j] = -2.f * fscale[col] * (1.f / 256.f);
    ysqj[j] = ysqA[col];
    yrj[j] = yrA[col];
  }
  #pragma unroll
  for (int i = 0; i < 4; ++i) {
    #pragma unroll
    for (int r = 0; r < 4; ++r) {
      int row = mBase + waveM * 64 + i * 16 + quad * 4 + r;
      float xs = xsA[row];
      float xr2 = 2.f * xrA[row];
      float partial = 0.f;
      if (xs >= 0.99999f) {
        // clipped row: z large -> sims~=1/(2z), e^u ~= 1+u+u^2/2
        #pragma unroll
        for (int j = 0; j < 4; ++j) {
          float d = fmaxf(fmaf(gj[j], acc[i][j][r], xs + ysqj[j]), 0.f);
          float z = fmaf(d, xr2 * yrj[j], 1.f);
          float u = 64.f * __builtin_amdgcn_rcpf(z);
          partial += fmaf(u, fmaf(0.5f, u, 1.f), 1.f);
        }
      } else {
        #pragma unroll
        for (int j = 0; j < 4; ++j) {
          float d = fmaxf(fmaf(gj[j], acc[i][j][r], xs + ysqj[j]), 0.f);
          float z = fmaf(d, xr2 * yrj[j], 1.f);
          float sq = sqrtf(fmaf(z, z, -1.f));
          float u = 128.f * __builtin_amdgcn_rcpf(z + sq);
          partial += __expf(u);
        }
      }
      partial += __shfl_xor(partial, 1);
      partial += __shfl_xor(partial, 2);
      partial += __shfl_xor(partial, 4);
      partial += __shfl_xor(partial, 8);
      if (l16 == 0) partials[(size_t)row * 256 + nt * 2 + waveN] = partial;
    }
  }
}

// wave-per-row exact fp32 label fix; returns row term (valid on lane 0)
__device__ __forceinline__ float final_row_term(
    int row, int lane,
    const float* __restrict__ x, const float* __restrict__ w,
    const int* __restrict__ labels, const float* __restrict__ fscale,
    const float* __restrict__ ysqA, const float* __restrict__ yrA,
    const float* __restrict__ xsA, const float* __restrict__ xrA,
    const float* __restrict__ partials)
{
  const float* pr = partials + (size_t)row * 256;
  float sum = pr[lane] + pr[lane + 64] + pr[lane + 128] + pr[lane + 192];

  int lab = labels[row];
  const float4* xv = (const float4*)(x + (size_t)row * Dn);
  const float4* wv4 = (const float4*)(w + (size_t)lab * Dn);
  float4 a0 = xv[lane * 2], a1 = xv[lane * 2 + 1];
  float4 b0 = wv4[lane * 2], b1 = wv4[lane * 2 + 1];
  float dot = a0.x * b0.x + a0.y * b0.y + a0.z * b0.z + a0.w * b0.w
            + a1.x * b1.x + a1.y * b1.y + a1.z * b1.z + a1.w * b1.w;
  #pragma unroll
  for (int d = 1; d < 64; d <<= 1) {
    sum += __shfl_xor(sum, d);
    dot += __shfl_xor(dot, d);
  }

  float term = 0.f;
  if (lane == 0) {
    float xy = fscale[lab] * dot;
    float diff = fmaxf(xsA[row] + ysqA[lab] - 2.f * xy, 0.f);
    float z = fmaf(2.f * diff, xrA[row] * yrA[lab], 1.f);
    float sq = sqrtf(fmaf(z, z, -1.f));
    float sims = 1.f / (z + sq);
    float u_lab = 128.f * sims;
    float cosv = fmaf(2.f, sims, -1.f);
    float sine = sqrtf(fmaxf(fmaf(-cosv, cosv, 1.f), 1e-7f));
    float phi = (cosv > -0.8775825619f)
                    ? (cosv * 0.8775825619f - sine * 0.4794255386f)
                    : (cosv - 0.2397127693f);
    float e_lab = __expf(u_lab);
    float e_phi = __expf(fminf(64.f * phi + 64.f, 80.f));
    term = logf(sum - e_lab + e_phi) - 64.f * phi - 64.f;
  }
  return term;
}

// ================= path A: one cooperative dispatch, grid-size adaptive =================
// Occupancy attack (this round): LDS 32KB/block allows 5 blocks/CU (5x32=160),
// regs ~140/wave << 2048/5 -> grid = 256*min(5,maxPerCU) = 1280 expected.
// 1280%8==0 keeps job&7 == bid&7 (XCD banding preserved for every t).
// Phase-2 tail shrinks: 3 serial jobs/block (G=768) -> 2 (G=1280).
// Phase 4 + its grid.sync removed: per-block term atomicAdd into out (memset'd).
__global__ __launch_bounds__(256, 3) void fused_kernel(
    const float* __restrict__ w, const float* __restrict__ x,
    const int* __restrict__ labels,
    char* __restrict__ wq8, char* __restrict__ xq8,
    float* __restrict__ fscale, float* __restrict__ ysqA, float* __restrict__ yrA,
    float* __restrict__ xsA, float* __restrict__ xrA,
    float* __restrict__ partials, float* __restrict__ out)
{
  __shared__ int4 ldsv[2048];  // 32 KB: buf{0,1} x [A 8K][W 8K]
  char* lds = (char*)ldsv;
  cg::grid_group grid = cg::this_grid();
  const int tid = threadIdx.x, lane = tid & 63, wv = tid >> 6;
  const int G = gridDim.x;
  const int gwv = (blockIdx.x << 2) | wv;   // global wave id
  const int wavesTotal = G << 2;

  // phase 1: prep (wave per row, grid-strided, 1-row software lookahead so the
  // next row's 2KB load is in flight under the current row's reduce/convert)
  {
    const int total = Cn + Bn;
    int row = gwv;
    float4 a = make_float4(0.f, 0.f, 0.f, 0.f), b = a;
    if (row < total) prep_load(row, lane, w, x, a, b);
    while (row < total) {
      int nrow = row + wavesTotal;
      float4 na = a, nb = b;
      if (nrow < total) prep_load(nrow, lane, w, x, na, nb);
      prep_row_vals(row, lane, a, b, wq8, xq8, fscale, ysqA, yrA, xsA, xrA);
      a = na; b = nb; row = nrow;
    }
  }
  grid.sync();

  // phase 2: gemm jobs, grid-strided
  #pragma unroll 1
  for (int job = blockIdx.x; job < 2048; job += G)
    gemm_job(job, tid, lds, xq8, wq8, fscale, ysqA, yrA, xsA, xrA, partials);
  grid.sync();

  // phase 3: label fix; one atomic per active block (replaces phase 4 + 3rd sync)
  if (blockIdx.x * 4 < Bn) {
    float mysum = 0.f;
    for (int row = gwv; row < Bn; row += wavesTotal)
      mysum += final_row_term(row, lane, x, w, labels, fscale, ysqA, yrA, xsA, xrA, partials);
    float* red = (float*)lds;  // gemm LDS dead (job-end barrier drained all reads)
    if (lane == 0) red[wv] = mysum;  // lane 0 holds the valid term
    __syncthreads();
    if (tid == 0)
      atomicAdd(out, (red[0] + red[1] + red[2] + red[3]) * (1.f / (float)Bn));
  }
}

// ================= path B: proven 4-dispatch fallback =================
__global__ __launch_bounds__(256) void prep_kernel(
    const float* __restrict__ w, const float* __restrict__ x,
    char* __restrict__ wq8, char* __restrict__ xq8,
    float* __restrict__ fscale, float* __restrict__ ysqA, float* __restrict__ yrA,
    float* __restrict__ xsA, float* __restrict__ xrA)
{
  int row = (blockIdx.x * 256 + threadIdx.x) >> 6;
  int lane = threadIdx.x & 63;
  float4 a, b;
  prep_load(row, lane, w, x, a, b);
  prep_row_vals(row, lane, a, b, wq8, xq8, fscale, ysqA, yrA, xsA, xrA);
}

__global__ __launch_bounds__(256, 3) void gemm_kernel(
    const char* __restrict__ xq8, const char* __restrict__ wq8,
    const float* __restrict__ fscale, const float* __restrict__ ysqA,
    const float* __restrict__ yrA, const float* __restrict__ xsA,
    const float* __restrict__ xrA, float* __restrict__ partials)
{
  __shared__ int4 ldsv[2048];  // 32 KB
  gemm_job(blockIdx.x, threadIdx.x, (char*)ldsv, xq8, wq8, fscale, ysqA, yrA, xsA, xrA, partials);
}

__global__ __launch_bounds__(256) void final_kernel(
    const float* __restrict__ x, const float* __restrict__ w,
    const int* __restrict__ labels, const float* __restrict__ fscale,
    const float* __restrict__ ysqA, const float* __restrict__ yrA,
    const float* __restrict__ xsA, const float* __restrict__ xrA,
    const float* __restrict__ partials, float* __restrict__ out)
{
  int row = blockIdx.x * 4 + (threadIdx.x >> 6);
  float term = final_row_term(row, threadIdx.x & 63, x, w, labels, fscale,
                              ysqA, yrA, xsA, xrA, partials);
  __shared__ float red[4];
  if ((threadIdx.x & 63) == 0) red[threadIdx.x >> 6] = term;
  __syncthreads();
  if (threadIdx.x == 0)
    atomicAdd(out, (red[0] + red[1] + red[2] + red[3]) * (1.f / (float)Bn));
}

extern "C" void kernel_launch(void* const* d_in, const int* in_sizes, int n_in,
                              void* d_out, int out_size, void* d_ws, size_t ws_size,
                              hipStream_t stream) {
  (void)in_sizes; (void)n_in; (void)out_size; (void)ws_size;
  const float* emb = (const float*)d_in[0];
  const int* labels = (const int*)d_in[1];
  const float* weight = (const float*)d_in[2];
  float* out = (float*)d_out;

  char* p = (char*)d_ws;
  char* wq8 = p; p += (size_t)Cn * Dn;       // 8 MB fp8
  char* xq8 = p; p += (size_t)Bn * Dn;       // 1 MB fp8
  float* fscale = (float*)p; p += (size_t)Cn * 4;
  float* ysqA  = (float*)p; p += (size_t)Cn * 4;
  float* yrA   = (float*)p; p += (size_t)Cn * 4;
  float* xsA   = (float*)p; p += (size_t)Bn * 4;
  float* xrA   = (float*)p; p += (size_t)Bn * 4;
  float* partials = (float*)p; p += (size_t)Bn * 256 * 4;  // 2 MB, written-once

  // both paths accumulate into out atomically
  hipMemsetAsync(out, 0, sizeof(float), stream);

  // deterministic guard: cooperative support + occupancy-adaptive grid
  int dev = 0;
  hipGetDevice(&dev);
  int coopAttr = 0;
  hipDeviceGetAttribute(&coopAttr, hipDeviceAttributeCooperativeLaunch, dev);
  int maxPerCU = 0;
  hipOccupancyMaxActiveBlocksPerMultiprocessor(&maxPerCU, (const void*)fused_kernel, 256, 0);

  hipError_t le = hipErrorUnknown;
  if (coopAttr == 1 && maxPerCU >= 2) {
    int perCU = maxPerCU < 5 ? maxPerCU : 5;   // LDS-bound cap: expect 5 -> grid 1280
    dim3 grid(256 * perCU);                    // 256*{2..5} all %8==0
    void* args[] = {(void*)&weight, (void*)&emb, (void*)&labels,
                    (void*)&wq8, (void*)&xq8, (void*)&fscale, (void*)&ysqA,
                    (void*)&yrA, (void*)&xsA, (void*)&xrA,
                    (void*)&partials, (void*)&out};
    le = hipLaunchCooperativeKernel((const void*)fused_kernel, grid, dim3(256),
                                    args, 0, stream);
  }
  if (le != hipSuccess) {
    // proven multi-dispatch path (R10 structure)
    prep_kernel<<<(Cn + Bn) / 4, 256, 0, stream>>>(weight, emb, wq8, xq8, fscale, ysqA, yrA, xsA, xrA);
    gemm_kernel<<<(Bn / 128) * (Cn / 128), 256, 0, stream>>>(
        xq8, wq8, fscale, ysqA, yrA, xsA, xrA, partials);
    final_kernel<<<Bn / 4, 256, 0, stream>>>(emb, weight, labels, fscale, ysqA, yrA, xsA, xrA, partials, out);
  }
}